// Round 12
// baseline (896.212 us; speedup 1.0000x reference)
//
#include <hip/hip_runtime.h>
#include <hip/hip_bf16.h>
#include <math.h>

#define N_NODES 100000
#define N_PAD   100096   // multiple of 256
#define N_EDGES 400000
#define IN_DIM  100
#define D       200
#define DP      208      // j padded to 13*16
#define KP      224      // k padded to 7*32
#define NUM_STEPS 4

#define TILE_SHORTS  21504         // full jt tile: 6 gates * 7 kt * 64 lanes * 8 shorts
#define HALF_SHORTS  10752         // 3 gates
#define HALF_GROUPS  21            // 1344 chunks / 64 lanes
#define EIDX_CAP     1536          // per-block LDS edge-index capacity (avg 512)

typedef __attribute__((ext_vector_type(8))) short bfrag;   // 8 bf16 (4 VGPRs)
typedef __attribute__((ext_vector_type(4))) float facc;    // 4 fp32

// Wc[s] = w_ih @ W[s]^T so that gi = aggr_raw @ Wc[s]^T  (scatter is linear)
__device__ float g_Wc[NUM_STEPS * 600 * D];
// weights, per-(step,jt) CONTIGUOUS tile: [s][jt][g6][t7][lane64][8]
__device__ short g_Wall[NUM_STEPS * 13 * TILE_SHORTS];
__device__ float g_bias[6 * DP];

__device__ __forceinline__ float fast_sigmoid(float x) {
    return __builtin_amdgcn_rcpf(1.0f + __expf(-x));
}
__device__ __forceinline__ float fast_tanh(float x) {
    return 2.0f * __builtin_amdgcn_rcpf(1.0f + __expf(-2.0f * x)) - 1.0f;
}
__device__ __forceinline__ float bf2f(short u) {
    unsigned int x = ((unsigned int)(unsigned short)u) << 16;
    return __uint_as_float(x);
}

// ---------------- Wc precompute: block=(s*600+j), thread=k ----------------
__global__ __launch_bounds__(256) void wc_kernel(const float* __restrict__ W,
                                                 const float* __restrict__ w_ih) {
    int s = blockIdx.x / 600;
    int j = blockIdx.x % 600;
    int k = threadIdx.x;
    if (k >= D) return;
    const float* wr = &w_ih[(size_t)j * D];
    const float* Wr = &W[(size_t)s * D * D + (size_t)k * D];
    float acc = 0.0f;
    #pragma unroll 4
    for (int t = 0; t < D; ++t) acc += wr[t] * Wr[t];
    g_Wc[((size_t)s * 600 + j) * D + k] = acc;
}

// ---------------- permute weights into per-tile fragment order (bf16) ----------------
// output idx = (((s*13 + jt)*6 + g)*7 + t)*64 + l, 8 shorts each
__global__ __launch_bounds__(256) void wconv_kernel(const float* __restrict__ w_hh) {
    int idx = blockIdx.x * 256 + threadIdx.x;   // < 4*13*6*7*64 = 139776
    int l  = idx & 63;
    int t  = (idx >> 6) % 7;
    int g  = (idx / 448) % 6;
    int jt = (idx / 2688) % 13;
    int s  = idx / 34944;
    int j  = jt * 16 + (l & 15);
    int k0 = t * 32 + (l >> 4) * 8;
    short* out = g_Wall + (size_t)idx * 8;
    #pragma unroll
    for (int i = 0; i < 8; ++i) {
        int k = k0 + i;
        float v = 0.0f;
        if (j < D && k < D)
            v = (g < 3) ? g_Wc[((size_t)s * 600 + g * 200 + j) * D + k]
                        : w_hh[((size_t)(g - 3) * 200 + j) * D + k];
        __hip_bfloat16 b = __float2bfloat16(v);
        out[i] = *reinterpret_cast<short*>(&b);
    }
}

__global__ void bias_kernel(const float* __restrict__ b_ih, const float* __restrict__ b_hh) {
    int idx = blockIdx.x * 256 + threadIdx.x;
    if (idx >= 6 * DP) return;
    int g = idx / DP, j = idx % DP;
    float v = 0.0f;
    if (j < D) v = (g < 3) ? b_ih[g * 200 + j] : b_hh[(g - 3) * 200 + j];
    g_bias[idx] = v;
}

// ---------------- pad: h[:, :100] = bf16(x), rest 0 ----------------
__global__ void pad_kernel(const float* __restrict__ x, __hip_bfloat16* __restrict__ h) {
    int idx = blockIdx.x * 256 + threadIdx.x;   // N_PAD*KP exact multiple of 256
    int n = idx / KP, c = idx % KP;
    float v = (n < N_NODES && c < IN_DIM) ? x[n * IN_DIM + c] : 0.0f;
    h[idx] = __float2bfloat16(v);
}

// ---------------- CSR build ----------------
__global__ void count_kernel(const int* __restrict__ dst, int* __restrict__ cnt) {
    int e = blockIdx.x * blockDim.x + threadIdx.x;
    if (e < N_EDGES) atomicAdd(&cnt[dst[e]], 1);
}

#define SCAN_B 1024
// 2-barrier block scan: wave shuffle-scan + cross-wave LDS
__global__ __launch_bounds__(SCAN_B) void scan1(const int* __restrict__ cnt,
                                                int* __restrict__ incl, int* __restrict__ bsum) {
    __shared__ int ws[16];
    int i = blockIdx.x * SCAN_B + threadIdx.x;
    int lane = threadIdx.x & 63, wid = threadIdx.x >> 6;
    int v = (i < N_NODES) ? cnt[i] : 0;
    int s = v;
    #pragma unroll
    for (int o = 1; o < 64; o <<= 1) {
        int t = __shfl_up(s, o, 64);
        if (lane >= o) s += t;
    }
    if (lane == 63) ws[wid] = s;
    __syncthreads();
    if (wid == 0) {
        int t = (lane < 16) ? ws[lane] : 0;
        #pragma unroll
        for (int o = 1; o < 16; o <<= 1) {
            int u = __shfl_up(t, o, 64);
            if (lane >= o) t += u;
        }
        if (lane < 16) ws[lane] = t;
    }
    __syncthreads();
    if (wid > 0) s += ws[wid - 1];
    if (i < N_NODES) incl[i] = s;
    if (threadIdx.x == SCAN_B - 1) bsum[blockIdx.x] = s;
}
__global__ void scan2(int* __restrict__ bsum, int nb) {
    __shared__ int sh[128];
    int v = (threadIdx.x < nb) ? bsum[threadIdx.x] : 0;
    sh[threadIdx.x] = v; __syncthreads();
    for (int off = 1; off < 128; off <<= 1) {
        int t = (threadIdx.x >= off) ? sh[threadIdx.x - off] : 0;
        __syncthreads();
        sh[threadIdx.x] += t;
        __syncthreads();
    }
    if (threadIdx.x < nb) bsum[threadIdx.x] = sh[threadIdx.x] - v;  // exclusive
}
__global__ void scan3(const int* __restrict__ cnt, const int* __restrict__ incl,
                      const int* __restrict__ bsum, int* __restrict__ off,
                      int* __restrict__ cursor) {
    int i = blockIdx.x * blockDim.x + threadIdx.x;
    if (i < N_NODES) {
        int v = incl[i] - cnt[i] + bsum[i / SCAN_B];
        off[i] = v; cursor[i] = v;
    }
    if (i == 0) off[N_NODES] = N_EDGES;
}
__global__ void fill_kernel(const int* __restrict__ src, const int* __restrict__ dst,
                            int* __restrict__ cursor, int* __restrict__ esrc) {
    int e = blockIdx.x * blockDim.x + threadIdx.x;
    if (e < N_EDGES) {
        int pos = atomicAdd(&cursor[dst[e]], 1);
        esrc[pos] = src[e];
    }
}

// ---------------- async stage: one HALF tile (21504 B) global -> LDS ----------------
__device__ __forceinline__ void stage_half(const short* __restrict__ gsrc,
                                           short* lds_dst, int wave, int lane) {
    #pragma unroll
    for (int g = wave; g < HALF_GROUPS; g += 4) {
        __builtin_amdgcn_global_load_lds(
            (const __attribute__((address_space(1))) void*)(gsrc + g * 512 + lane * 8),
            (__attribute__((address_space(3))) void*)(lds_dst + g * 512),
            16, 0, 0);
    }
}

// ---------------- fused gather + MFMA GRU (+ pool on last step) ----------------
// grid N_PAD/128; block 256 = 4 waves; wave: 32 rows (MFMA phase).
// Gather: block-cooperative, DYNAMICALLY balanced. 2 phases x 64 rows through a
//   28.7KB LDS scratch (aliases B buffers). 8 groups of 32 threads grab rows from
//   an LDS atomic counter; each thread sums one 16B chunk over the row's edges
//   (indices pre-cached in LDS). Waves 2p,2p+1 read their av frags after phase p.
// MFMA phase: 26 half-tile iterations, double-buffered global_load_lds DMA.
__global__ __launch_bounds__(256, 2) void gru_fused(const __hip_bfloat16* __restrict__ hcur,
                                                    __hip_bfloat16* __restrict__ hnext,
                                                    const int* __restrict__ off,
                                                    const int* __restrict__ esrc,
                                                    unsigned int* __restrict__ pooled,
                                                    int step) {
    __shared__ short Bs[2][HALF_SHORTS];  // 43008 B; shorts 7168..21503 = gather scratch
    __shared__ int eidx[EIDX_CAP];        // 6144 B edge-index cache
    __shared__ int offs[129];             // block CSR offsets
    __shared__ int rowctr;                // dynamic row counter
    __shared__ unsigned int pmax[DP];     // step-3 pooling scratch
    int tid = threadIdx.x;
    int lane = tid & 63, wave = tid >> 6;
    int blk0 = blockIdx.x * 128;
    int wbase = blk0 + wave * 32;
    int mrow = lane & 15, kq = lane >> 4;
    bool dopool = (step == NUM_STEPS - 1);

    if (dopool) for (int c = tid; c < DP; c += 256) pmax[c] = 0u;

    // ---- prefetch block CSR offsets + edge indices ----
    for (int i = tid; i < 129; i += 256) {
        int n = blk0 + i;
        offs[i] = off[n < N_NODES ? n : N_NODES];
    }
    __syncthreads();
    int lo = offs[0];
    int cntb = offs[128] - lo;
    bool use_lds = (cntb <= EIDX_CAP);
    if (use_lds)
        for (int i = tid; i < cntb; i += 256) eidx[i] = esrc[lo + i];

    short* scr = &Bs[0][0] + 7168;        // 64 rows x 224 shorts (28672 B)
    bfrag av[2][7], hv[2][7];

    int group_src = lane & 32;            // shfl source lane for this half-wave group
    int ck = tid & 31;                    // chunk id within group (0..27 used)
    int colA = ck * 8;

    #pragma unroll
    for (int p = 0; p < 2; ++p) {
        if (tid == 0) rowctr = 0;
        __syncthreads();   // scratch free (prev frags read), eidx ready, ctr reset
        for (;;) {
            int r = 0;
            if ((tid & 31) == 0) r = atomicAdd(&rowctr, 1);
            r = __shfl(r, group_src, 64);
            if (r >= 64) break;
            int row = p * 64 + r;
            int e0 = offs[row] - lo, e1 = offs[row + 1] - lo;
            float a[8] = {0, 0, 0, 0, 0, 0, 0, 0};
            if (ck < 25) {
                int e = e0;
                for (; e + 3 < e1; e += 4) {
                    int i0, i1, i2, i3;
                    if (use_lds) {
                        i0 = eidx[e]; i1 = eidx[e + 1]; i2 = eidx[e + 2]; i3 = eidx[e + 3];
                    } else {
                        i0 = esrc[lo + e];     i1 = esrc[lo + e + 1];
                        i2 = esrc[lo + e + 2]; i3 = esrc[lo + e + 3];
                    }
                    bfrag a0 = *(const bfrag*)(hcur + (size_t)i0 * KP + colA);
                    bfrag a1 = *(const bfrag*)(hcur + (size_t)i1 * KP + colA);
                    bfrag a2 = *(const bfrag*)(hcur + (size_t)i2 * KP + colA);
                    bfrag a3 = *(const bfrag*)(hcur + (size_t)i3 * KP + colA);
                    #pragma unroll
                    for (int q = 0; q < 8; ++q)
                        a[q] += (bf2f(a0[q]) + bf2f(a1[q])) + (bf2f(a2[q]) + bf2f(a3[q]));
                }
                for (; e < e1; ++e) {
                    int i0 = use_lds ? eidx[e] : esrc[lo + e];
                    bfrag a0 = *(const bfrag*)(hcur + (size_t)i0 * KP + colA);
                    #pragma unroll
                    for (int q = 0; q < 8; ++q) a[q] += bf2f(a0[q]);
                }
            }
            if (ck < 28) {
                __hip_bfloat16 o[8];
                #pragma unroll
                for (int q = 0; q < 8; ++q) o[q] = __float2bfloat16(a[q]);
                *(ushort4*)(scr + r * KP + colA)     = *(const ushort4*)&o[0];
                *(ushort4*)(scr + r * KP + colA + 4) = *(const ushort4*)&o[4];
            }
        }
        __syncthreads();   // phase-p scratch complete
        if ((wave >> 1) == p) {
            int sbase = (wave & 1) * 32;
            #pragma unroll
            for (int mf = 0; mf < 2; ++mf)
                #pragma unroll
                for (int t = 0; t < 7; ++t)
                    av[mf][t] = *(const bfrag*)&scr[(sbase + mf * 16 + mrow) * KP + t * 32 + kq * 8];
        }
    }

    // ---- load this wave's H fragments from global (contiguous rows) ----
    size_t hbase = (size_t)(wbase + mrow) * KP + kq * 8;
    #pragma unroll
    for (int mf = 0; mf < 2; ++mf)
        #pragma unroll
        for (int t = 0; t < 7; ++t)
            hv[mf][t] = *(const bfrag*)(hcur + hbase + mf * 16 * KP + t * 32);

    const short* Wstep = g_Wall + (size_t)step * 13 * TILE_SHORTS;
    int jcol = lane & 15;
    int rowq = (lane >> 4) * 4;

    __syncthreads();                       // all frag reads done; LDS -> B buffers
    stage_half(Wstep, &Bs[0][0], wave, lane);   // h0 = (jt0, gi-gates)

    facc acc[6][2];
    unsigned short hold_u[2][4];

    for (int hk = 0; hk < 26; ++hk) {
        __syncthreads();   // h_hk DMA complete; buf[(hk+1)&1] free for restage
        if (hk + 1 < 26)
            stage_half(Wstep + (size_t)(hk + 1) * HALF_SHORTS,
                       &Bs[(hk + 1) & 1][0], wave, lane);

        int jt = hk >> 1;
        int j = jt * 16 + jcol;
        const short* Bcur = &Bs[hk & 1][0];

        if ((hk & 1) == 0) {
            // preload old-h for this jt's epilogue (latency hides under both halves)
            #pragma unroll
            for (int mf = 0; mf < 2; ++mf)
                #pragma unroll
                for (int r = 0; r < 4; ++r)
                    hold_u[mf][r] = *(const unsigned short*)
                        (hcur + (size_t)(wbase + mf * 16 + rowq + r) * KP + j);
            #pragma unroll
            for (int g = 0; g < 6; ++g)
                #pragma unroll
                for (int mf = 0; mf < 2; ++mf) acc[g][mf] = (facc)(0.0f);
            // gi gates (0..2) consume av
            #pragma unroll
            for (int t = 0; t < 7; ++t) {
                bfrag bv[3];
                #pragma unroll
                for (int g = 0; g < 3; ++g)
                    bv[g] = *(const bfrag*)&Bcur[(size_t)(((g * 7 + t) * 64) + lane) * 8];
                #pragma unroll
                for (int g = 0; g < 3; ++g)
                    #pragma unroll
                    for (int mf = 0; mf < 2; ++mf)
                        acc[g][mf] = __builtin_amdgcn_mfma_f32_16x16x32_bf16(av[mf][t], bv[g], acc[g][mf], 0, 0, 0);
            }
        } else {
            // gh gates (3..5) consume hv
            #pragma unroll
            for (int t = 0; t < 7; ++t) {
                bfrag bv[3];
                #pragma unroll
                for (int g = 0; g < 3; ++g)
                    bv[g] = *(const bfrag*)&Bcur[(size_t)(((g * 7 + t) * 64) + lane) * 8];
                #pragma unroll
                for (int g = 0; g < 3; ++g)
                    #pragma unroll
                    for (int mf = 0; mf < 2; ++mf)
                        acc[g + 3][mf] = __builtin_amdgcn_mfma_f32_16x16x32_bf16(hv[mf][t], bv[g], acc[g + 3][mf], 0, 0, 0);
            }

            // epilogue: C/D layout col=lane&15 (j), row=(lane>>4)*4+reg (m)
            float tmax = 0.0f;
            if (j < D) {
                float bir = g_bias[j],          biz = g_bias[DP + j],     bin = g_bias[2 * DP + j];
                float bhr = g_bias[3 * DP + j], bhz = g_bias[4 * DP + j], bhn = g_bias[5 * DP + j];
                #pragma unroll
                for (int mf = 0; mf < 2; ++mf) {
                    int m0 = wbase + mf * 16 + rowq;
                    #pragma unroll
                    for (int r = 0; r < 4; ++r) {
                        int m = m0 + r;
                        if (m < N_NODES) {
                            float hold = bf2f((short)hold_u[mf][r]);
                            float rr = fast_sigmoid(acc[0][mf][r] + bir + acc[3][mf][r] + bhr);
                            float zz = fast_sigmoid(acc[1][mf][r] + biz + acc[4][mf][r] + bhz);
                            float nn = fast_tanh(acc[2][mf][r] + bin + rr * (acc[5][mf][r] + bhn));
                            float hv2 = (1.0f - zz) * nn + zz * hold;
                            hnext[(size_t)m * KP + j] = __float2bfloat16(hv2);
                            if (hv2 > tmax) tmax = hv2;
                        }
                    }
                }
                if (dopool) atomicMax(&pmax[j], __float_as_uint(tmax));
            }
        }
    }

    if (dopool) {
        __syncthreads();
        for (int c = tid; c < D; c += 256) atomicMax(&pooled[c], pmax[c]);
    }
}

// ---------------- logits + softmax ----------------
__global__ void head_kernel(const unsigned int* __restrict__ pooled,
                            const float* __restrict__ cls_w,
                            const float* __restrict__ cls_b,
                            float* __restrict__ out) {
    if (threadIdx.x == 0) {
        float l0 = cls_b[0], l1 = cls_b[1];
        for (int d = 0; d < D; ++d) {
            float p = __uint_as_float(pooled[d]);
            l0 += p * cls_w[d];
            l1 += p * cls_w[D + d];
        }
        float mx = l0 > l1 ? l0 : l1;
        float e0 = expf(l0 - mx), e1 = expf(l1 - mx);
        out[0] = e0 / (e0 + e1);
        out[1] = e1 / (e0 + e1);
    }
}

extern "C" void kernel_launch(void* const* d_in, const int* in_sizes, int n_in,
                              void* d_out, int out_size, void* d_ws, size_t ws_size,
                              hipStream_t stream) {
    const float* x     = (const float*)d_in[0];
    const float* W     = (const float*)d_in[1];
    const float* w_ih  = (const float*)d_in[2];
    const float* w_hh  = (const float*)d_in[3];
    const float* b_ih  = (const float*)d_in[4];
    const float* b_hh  = (const float*)d_in[5];
    const float* cls_w = (const float*)d_in[6];
    const float* cls_b = (const float*)d_in[7];
    const int*   ei    = (const int*)d_in[8];
    const int* src = ei;
    const int* dst = ei + N_EDGES;

    const size_t ROWB = (size_t)N_PAD * KP;     // bf16 elements per buffer
    __hip_bfloat16* hA   = (__hip_bfloat16*)d_ws;
    __hip_bfloat16* hB   = hA + ROWB;
    int* cnt    = (int*)(hB + ROWB);
    int* incl   = cnt + N_NODES;
    int* bsum   = incl + N_NODES;
    int* off    = bsum + 128;
    int* cursor = off + N_NODES + 1;
    int* esrc   = cursor + N_NODES;
    unsigned int* pooled = (unsigned int*)(esrc + N_EDGES);

    // CSR build (once per call; edges are step-invariant)
    hipMemsetAsync(cnt, 0, N_NODES * sizeof(int), stream);
    count_kernel<<<(N_EDGES + 255) / 256, 256, 0, stream>>>(dst, cnt);
    scan1<<<(N_NODES + SCAN_B - 1) / SCAN_B, SCAN_B, 0, stream>>>(cnt, incl, bsum);
    scan2<<<1, 128, 0, stream>>>(bsum, (N_NODES + SCAN_B - 1) / SCAN_B);
    scan3<<<(N_NODES + 255) / 256, 256, 0, stream>>>(cnt, incl, bsum, off, cursor);
    fill_kernel<<<(N_EDGES + 255) / 256, 256, 0, stream>>>(src, dst, cursor, esrc);

    // weight prep
    wc_kernel<<<NUM_STEPS * 600, 256, 0, stream>>>(W, w_ih);
    wconv_kernel<<<(NUM_STEPS * 13 * 6 * 7 * 64) / 256, 256, 0, stream>>>(w_hh);
    bias_kernel<<<(6 * DP + 255) / 256, 256, 0, stream>>>(b_ih, b_hh);

    pad_kernel<<<(int)(ROWB / 256), 256, 0, stream>>>(x, hA);
    hipMemsetAsync(pooled, 0, D * sizeof(unsigned int), stream);

    __hip_bfloat16* hcur = hA;
    __hip_bfloat16* hnext = hB;
    for (int s = 0; s < NUM_STEPS; ++s) {
        gru_fused<<<N_PAD / 128, 256, 0, stream>>>(hcur, hnext, off, esrc, pooled, s);
        __hip_bfloat16* t = hcur; hcur = hnext; hnext = t;
    }
    head_kernel<<<1, 64, 0, stream>>>(pooled, cls_w, cls_b, (float*)d_out);
}